// Round 14
// baseline (102.749 us; speedup 1.0000x reference)
//
#include <hip/hip_runtime.h>
#include <hip/hip_bf16.h>

// ---------------------------------------------------------------------------
// EnhancedUFormerBlock: LN1 -> QKV(+V^T fold) -> halo attention ->
//                       proj(+res)+LN2 -> fused MLP(GELU+fc2+res) -> NCHW.
// Harness I/O dtype: float32 (per reference). Internals: bf16 MFMA.
// Only 16x16x32 MFMA fragment layouts are used (HW-validated rounds 2-8).
// attn (r14): P round-trip through LDS ELIMINATED via the sigma-permutation
// trick -- PV computed as OUT^T = mfma(A=V^T-frag, B=P-frag) where both
// operands index k through sigma(lg,e) = lg*4+(e>>1)+16*(e&1); the QK^T
// cvt_pk output IS the PV B-frag (zero rearrangement). DS ops/kr: 8 -> 2.
// q-granularity frozen at 32 (r7 regression, r9/r10 64q failures).
// GEMMs: 1-wave 64x64 tiles (r11). MLP: fc1+GELU+fc2 fused in LDS (r13).
// ---------------------------------------------------------------------------

typedef __attribute__((ext_vector_type(8))) short bf16x8;
typedef __attribute__((ext_vector_type(4))) float f32x4;
typedef __attribute__((ext_vector_type(4))) unsigned int u32x4;

#define MFMA16(a, b, c) __builtin_amdgcn_mfma_f32_16x16x32_bf16((a), (b), (c), 0, 0, 0)

__device__ __forceinline__ float u2f(unsigned short u) {
  unsigned int x = ((unsigned int)u) << 16;
  return __builtin_bit_cast(float, x);
}
__device__ __forceinline__ unsigned short f2u(float f) {
  unsigned int x = __builtin_bit_cast(unsigned int, f);
  x += 0x7FFFu + ((x >> 16) & 1u);   // RNE
  return (unsigned short)(x >> 16);
}
__device__ __forceinline__ unsigned int cvt_pk_bf16(float lo, float hi) {
  unsigned int r;
  asm("v_cvt_pk_bf16_f32 %0, %1, %2" : "=v"(r) : "v"(lo), "v"(hi));
  return r;
}
__device__ __forceinline__ float gelu_f(float v) {
  const float y = 0.7978845608f * (v + 0.044715f * v * v * v);
  const float E = __builtin_amdgcn_exp2f(y * 2.8853900818f);
  return v - v * __builtin_amdgcn_rcpf(E + 1.0f);
}

#define QSCALE 0.36067376022224085f   // 0.25 * log2(e)

// ws layout (bytes). Aliases safe per kernel ordering:
//   attnb <- h1 (dead after QKV), h2 <- qb (dead after attn).
#define O_XHT 0ull                      // f32 residual 1 [16384][128]  8MB
#define O_H1  (8ull << 20)              // bf16 LN1 out   [16384][128]  4MB
#define O_QB  (12ull << 20)             // bf16 Q (pre-scaled)          4MB
#define O_XH1 (16ull << 20)             // f32 residual 2 [16384][128]  8MB
#define O_KP  (24ull << 20)             // bf16 K padded  [144*144][128]
#define O_VPT (O_KP + 5308416ull)       // bf16 V^T       [128][144*144]
#define O_WB  (O_KP + (16ull << 20))    // bf16 weights   ~384KB
#define PADT  20736                     // 144*144 padded tokens

// --------------- setup: weight cvt + kp pad zero + vpt pad zero ------------
__global__ __launch_bounds__(256) void setup_kernel(
    const float* __restrict__ a, const float* __restrict__ b,
    const float* __restrict__ c, const float* __restrict__ d,
    unsigned short* __restrict__ wb,
    unsigned short* __restrict__ kp, unsigned short* __restrict__ vpt) {
  const int bx = blockIdx.x, tid = threadIdx.x;
  if (bx < 192) {
    const int i = (bx * 256 + tid) * 4;
    const float* s; int lo;
    if (i < 49152)       { s = a; lo = 0; }
    else if (i < 65536)  { s = b; lo = 49152; }
    else if (i < 131072) { s = c; lo = 65536; }
    else                 { s = d; lo = 131072; }
    const float4 v = *(const float4*)(s + (i - lo));
    ushort4 o;
    o.x = f2u(v.x); o.y = f2u(v.y); o.z = f2u(v.z); o.w = f2u(v.w);
    *(ushort4*)(wb + i) = o;
  } else if (bx < 209) {
    const int idx = (bx - 192) * 256 + tid;
    if (idx >= 4352) return;
    int r, cc;
    if (idx < 2304) {               // top 8 + bottom 8 full rows (16 x 144)
      const int rr = idx / 144;
      r = (rr < 8) ? rr : rr + 128;
      cc = idx - rr * 144;
    } else {                        // side cols of rows 8..135 (128 x 16)
      const int i2 = idx - 2304;
      r = 8 + (i2 >> 4);
      const int c2 = i2 & 15;
      cc = (c2 < 8) ? c2 : c2 + 128;
    }
    const size_t off = ((size_t)r * 144 + cc) * 128;
    const u32x4 z = {};
#pragma unroll
    for (int k = 0; k < 16; k++) *(u32x4*)(kp + off + k * 8) = z;
  } else {
    const int ch = bx - 209;
    unsigned short* base = vpt + (size_t)ch * PADT;
    const u32x4 z = {};
    if (tid < 144) {
      *(u32x4*)(base + tid * 8) = z;            // top rows, tok 0..1151
      *(u32x4*)(base + 19584 + tid * 8) = z;    // bottom rows
    }
    const int hr = tid >> 1, side = tid & 1;    // side runs, rows 8..135
    *(u32x4*)(base + (hr + 8) * 144 + side * 136) = z;
  }
}

// ------------- LN1 + NCHW->NHWC via LDS transpose tile ---------------------
__global__ __launch_bounds__(256) void ln1_kernel(
    const float* __restrict__ x,
    const float* __restrict__ lw, const float* __restrict__ lb,
    float* __restrict__ xh_t, unsigned short* __restrict__ h1) {
  __shared__ float ld[128][33];
  const int t0 = blockIdx.x * 32;
  const int tid = threadIdx.x;
  {
    const int c = tid >> 1, th = (tid & 1) * 16;
    const float* src = x + (size_t)c * 16384 + t0 + th;
#pragma unroll
    for (int i = 0; i < 4; i++) {
      const float4 v = *(const float4*)(src + i * 4);
      ld[c][th + i * 4]     = v.x;
      ld[c][th + i * 4 + 1] = v.y;
      ld[c][th + i * 4 + 2] = v.z;
      ld[c][th + i * 4 + 3] = v.w;
    }
  }
  __syncthreads();
  const int t = tid >> 3, cp = (tid & 7) * 16;
  float vals[16];
  float s = 0.f, q = 0.f;
#pragma unroll
  for (int i = 0; i < 16; i++) {
    const float v = ld[cp + i][t];
    vals[i] = v;
    s += v; q += v * v;
  }
  s += __shfl_xor(s, 1); q += __shfl_xor(q, 1);
  s += __shfl_xor(s, 2); q += __shfl_xor(q, 2);
  s += __shfl_xor(s, 4); q += __shfl_xor(q, 4);
  const float mu = s * 0.0078125f;
  const float rs = rsqrtf(q * 0.0078125f - mu * mu + 1e-5f);
  float* xrow = xh_t + (size_t)(t0 + t) * 128 + cp;
#pragma unroll
  for (int i = 0; i < 4; i++)
    *(float4*)(xrow + i * 4) =
        float4{vals[4*i], vals[4*i+1], vals[4*i+2], vals[4*i+3]};
  unsigned int pk[8];
#pragma unroll
  for (int k = 0; k < 8; k++) {
    const float y0 = (vals[2*k]   - mu) * rs * lw[cp + 2*k]   + lb[cp + 2*k];
    const float y1 = (vals[2*k+1] - mu) * rs * lw[cp + 2*k+1] + lb[cp + 2*k+1];
    pk[k] = cvt_pk_bf16(y0, y1);
  }
  unsigned int* hrow = (unsigned int*)(h1 + (size_t)(t0 + t) * 128 + cp);
  *(u32x4*)(hrow)     = u32x4{pk[0], pk[1], pk[2], pk[3]};
  *(u32x4*)(hrow + 4) = u32x4{pk[4], pk[5], pk[6], pk[7]};
}

// ------------------------- QKV GEMM (1-wave 64x64) -------------------------
__global__ __launch_bounds__(64) void qkv_kernel(
    const unsigned short* __restrict__ A,
    const unsigned short* __restrict__ B,
    const float* __restrict__ bias,
    unsigned short* __restrict__ qb,
    unsigned short* __restrict__ kp,
    unsigned short* __restrict__ vpt) {
  const int tid = threadIdx.x;
  const int lr = tid & 15, lg = tid >> 4;
  const int mB = blockIdx.x * 64, nB = blockIdx.y * 64;
  f32x4 acc[4][4] = {};
  const unsigned short* Ab = A + (size_t)(mB + lr) * 128 + lg * 8;
  const unsigned short* Bb = B + (size_t)(nB + lr) * 128 + lg * 8;
  for (int k = 0; k < 128; k += 32) {
    bf16x8 a[4], b[4];
#pragma unroll
    for (int i = 0; i < 4; i++) {
      a[i] = *(const bf16x8*)(Ab + (size_t)i * 16 * 128 + k);
      b[i] = *(const bf16x8*)(Bb + (size_t)i * 16 * 128 + k);
    }
#pragma unroll
    for (int i = 0; i < 4; i++)
#pragma unroll
      for (int j = 0; j < 4; j++)
        acc[i][j] = MFMA16(a[i], b[j], acc[i][j]);
  }

  if (nB < 256) {   // Q (nB<128) or K (128<=nB<256): per-element stores
#pragma unroll
    for (int j = 0; j < 4; j++) {
      const int jj = nB + j * 16 + lr;
      const float bv = bias[jj];
#pragma unroll
      for (int i = 0; i < 4; i++)
#pragma unroll
        for (int r = 0; r < 4; r++) {
          const int ii = mB + i * 16 + lg * 4 + r;
          const float v = acc[i][j][r] + bv;
          if (jj < 128) {
            qb[(size_t)ii * 128 + jj] = f2u(v * QSCALE);
          } else {
            const int gh = ii >> 7, gw = ii & 127;
            const size_t prow = (size_t)(gh + 8) * 144 + (gw + 8);
            kp[prow * 128 + (jj - 128)] = f2u(v);
          }
        }
    }
  } else {          // V: LDS transpose -> coalesced V^T row stores
    __shared__ __align__(16) unsigned short tbv[64][72];
#pragma unroll
    for (int j = 0; j < 4; j++) {
      const int jl = j * 16 + lr;
      const float bv = bias[nB + jl];
#pragma unroll
      for (int i = 0; i < 4; i++)
#pragma unroll
        for (int r = 0; r < 4; r++) {
          const int il = i * 16 + lg * 4 + r;
          tbv[jl][il] = f2u(acc[i][j][r] + bv);
        }
    }
    __syncthreads();
    const int gh = mB >> 7, gw0 = mB & 127;     // 64|mB, no row wrap
    const size_t prow0 = (size_t)(gh + 8) * 144 + gw0 + 8;
    unsigned short* dst = vpt + (size_t)(nB - 256 + tid) * PADT + prow0;
#pragma unroll
    for (int t8 = 0; t8 < 8; t8++)
      *(u32x4*)(dst + t8 * 8) = *(const u32x4*)&tbv[tid][t8 * 8];
  }
}

// ---------------- proj GEMM + residual + LN2 (fused) -----------------------
__global__ __launch_bounds__(256) void projln2_kernel(
    const unsigned short* __restrict__ A,    // attnb
    const unsigned short* __restrict__ B,    // proj_wb
    const float* __restrict__ bias,
    const float* __restrict__ xh_t,
    const float* __restrict__ lw, const float* __restrict__ lb,
    float* __restrict__ xh1, unsigned short* __restrict__ h2) {
  __shared__ float sred[4][16][2];
  const int tid = threadIdx.x;
  const int w = tid >> 6, l = tid & 63;
  const int lr = l & 15, lg = l >> 4;
  const int mB = blockIdx.x * 16;
  const int n0 = w * 32;
  f32x4 acc[2] = {};
  const unsigned short* Ar = A + (size_t)(mB + lr) * 128 + lg * 8;
  const unsigned short* Br0 = B + (size_t)(n0 + lr) * 128 + lg * 8;
  const unsigned short* Br1 = Br0 + 16 * 128;
  for (int k = 0; k < 128; k += 32) {
    const bf16x8 a  = *(const bf16x8*)(Ar + k);
    const bf16x8 b0 = *(const bf16x8*)(Br0 + k);
    const bf16x8 b1 = *(const bf16x8*)(Br1 + k);
    acc[0] = MFMA16(a, b0, acc[0]);
    acc[1] = MFMA16(a, b1, acc[1]);
  }
  float vv[2][4];   // [j][r]
#pragma unroll
  for (int j = 0; j < 2; j++) {
    const int jj = n0 + j * 16 + lr;
    const float bv = bias[jj];
#pragma unroll
    for (int r = 0; r < 4; r++) {
      const int ii = mB + lg * 4 + r;
      const float v = acc[j][r] + bv + xh_t[(size_t)ii * 128 + jj];
      xh1[(size_t)ii * 128 + jj] = v;
      vv[j][r] = v;
    }
  }
#pragma unroll
  for (int r = 0; r < 4; r++) {
    float s = vv[0][r] + vv[1][r];
    float q = vv[0][r] * vv[0][r] + vv[1][r] * vv[1][r];
    s += __shfl_xor(s, 1); q += __shfl_xor(q, 1);
    s += __shfl_xor(s, 2); q += __shfl_xor(q, 2);
    s += __shfl_xor(s, 4); q += __shfl_xor(q, 4);
    s += __shfl_xor(s, 8); q += __shfl_xor(q, 8);
    if (lr == 0) {
      sred[w][lg * 4 + r][0] = s;
      sred[w][lg * 4 + r][1] = q;
    }
  }
  __syncthreads();
#pragma unroll
  for (int r = 0; r < 4; r++) {
    const int tok = lg * 4 + r;
    const float s = sred[0][tok][0] + sred[1][tok][0] +
                    sred[2][tok][0] + sred[3][tok][0];
    const float q = sred[0][tok][1] + sred[1][tok][1] +
                    sred[2][tok][1] + sred[3][tok][1];
    const float mu = s * 0.0078125f;
    const float rs = rsqrtf(q * 0.0078125f - mu * mu + 1e-5f);
#pragma unroll
    for (int j = 0; j < 2; j++) {
      const int jj = n0 + j * 16 + lr;
      const float y = (vv[j][r] - mu) * rs * lw[jj] + lb[jj];
      h2[(size_t)(mB + tok) * 128 + jj] = f2u(y);
    }
  }
}

// ------------------- fused MLP: fc1 + GELU + fc2 + residual ----------------
__global__ __launch_bounds__(256) void mlp_kernel(
    const unsigned short* __restrict__ h2,
    const unsigned short* __restrict__ fc1_wb,
    const float* __restrict__ fc1_b,
    const unsigned short* __restrict__ fc2_wb,
    const float* __restrict__ fc2_b,
    const float* __restrict__ xh1,
    float* __restrict__ outp) {
  __shared__ __align__(16) char smem[66560];
  unsigned short (*m_lds)[520] = (unsigned short(*)[520])smem;
  float (*tb)[68] = (float(*)[68])smem;

  const int tid = threadIdx.x;
  const int w = tid >> 6, l = tid & 63;
  const int lr = l & 15, lg = l >> 4;
  const int mB = blockIdx.x * 64;

  // ---- phase 1: m[t][n] = GELU(h2 @ fc1^T + b), wave w: n in [w*128, ...)
  {
    f32x4 acc[8][4] = {};
    const unsigned short* Ab = fc1_wb + (size_t)(w * 128 + lr) * 128 + lg * 8;
    const unsigned short* Bb = h2 + (size_t)(mB + lr) * 128 + lg * 8;
    for (int k = 0; k < 128; k += 32) {
      bf16x8 a[8], b[4];
#pragma unroll
      for (int i = 0; i < 8; i++)
        a[i] = *(const bf16x8*)(Ab + (size_t)i * 16 * 128 + k);
#pragma unroll
      for (int j = 0; j < 4; j++)
        b[j] = *(const bf16x8*)(Bb + (size_t)j * 16 * 128 + k);
#pragma unroll
      for (int i = 0; i < 8; i++)
#pragma unroll
        for (int j = 0; j < 4; j++)
          acc[i][j] = MFMA16(a[i], b[j], acc[i][j]);
    }
    // D[n][t]: n = w*128 + i*16 + lg*4 + r, t = j*16 + lr
#pragma unroll
    for (int i = 0; i < 8; i++) {
      const int n0 = w * 128 + i * 16 + lg * 4;
      const float4 b4 = *(const float4*)(fc1_b + n0);
#pragma unroll
      for (int j = 0; j < 4; j++) {
        const int t = j * 16 + lr;
        const float g0 = gelu_f(acc[i][j][0] + b4.x);
        const float g1 = gelu_f(acc[i][j][1] + b4.y);
        const float g2 = gelu_f(acc[i][j][2] + b4.z);
        const float g3 = gelu_f(acc[i][j][3] + b4.w);
        uint2 pk;
        pk.x = cvt_pk_bf16(g0, g1);
        pk.y = cvt_pk_bf16(g2, g3);
        *(uint2*)&m_lds[t][n0] = pk;
      }
    }
  }
  __syncthreads();

  // ---- phase 2: out[t][c] = m @ fc2^T + bias + xh1; wave w: c in [w*32,...)
  f32x4 acc2[4][2] = {};
  {
    const unsigned short* Bb = fc2_wb + (size_t)(w * 32 + lr) * 512 + lg * 8;
    for (int k = 0; k < 512; k += 32) {
      bf16x8 a[4], b[2];
#pragma unroll
      for (int i = 0; i < 4; i++)
        a[i] = *(const bf16x8*)&m_lds[i * 16 + lr][k + lg * 8];
#pragma unroll
      for (int j = 0; j < 2; j++)
        b[j] = *(const bf16x8*)(Bb + (size_t)j * 16 * 512 + k);
#pragma unroll
      for (int i = 0; i < 4; i++)
#pragma unroll
        for (int j = 0; j < 2; j++)
          acc2[i][j] = MFMA16(a[i], b[j], acc2[i][j]);
    }
  }
  __syncthreads();   // all waves done reading m before tb overwrites it

#pragma unroll
  for (int j = 0; j < 2; j++) {
    const int jj = w * 32 + j * 16 + lr;       // channel
    const float bv = fc2_b[jj];
#pragma unroll
    for (int i = 0; i < 4; i++)
#pragma unroll
      for (int r = 0; r < 4; r++) {
        const int il = i * 16 + lg * 4 + r;    // token within block
        tb[jj][il] = acc2[i][j][r] + bv +
                     xh1[(size_t)(mB + il) * 128 + jj];
      }
  }
  __syncthreads();
  {
    const int c = tid >> 1, seg = (tid & 1) * 32;
    float* op = outp + (size_t)c * 16384 + mB + seg;
#pragma unroll
    for (int q = 0; q < 8; q++)
      *(float4*)(op + q * 4) = *(const float4*)&tb[c][seg + q * 4];
  }
}

// ------------------------------ halo attention -----------------------------
// r8 structure + LDS-staged K (r12) + sigma-permutation PV (r14):
// block = (win, head, qhalf), win=bid&63, 4 waves x 32 queries.
// QK^T (validated): s = mfma(kf, qf) -> lane (lr,lg) holds
// P[key=lg*4+r][q=lr] and P[key=16+lg*4+r][q=lr]. cvt_pk packs word r =
// (P[lg*4+r], P[16+lg*4+r]); under sigma(lg,e)=lg*4+(e>>1)+16*(e&1) this
// u32x4 IS a valid MFMA B-frag (col=q=lr). The V^T A-frag uses the SAME
// sigma: word r = (V[lg*4+r][d=lr], V[16+lg*4+r][d=lr]) built from 2x 8B
// loads + 4 v_perm (once per kr, shared across qt). Since both operands
// index k via sigma, OUT^T[d][q] = mfma(vfrag, pfrag) is exact.
// Denominator: den = mfma(ones_as_A, pfrag) -> D[any row][q=lr] = sum P.
// Output: lane holds OUT[q=lr][d=lg*4+..+3] -> one 8B store per qt.
// Q pre-scaled by 0.25*log2(e); zero-padded OOB keys: P=1, V=0 (matches
// reference softmax exactly, as since r2).
__global__ __launch_bounds__(256) void attn_kernel(
    const unsigned short* __restrict__ qb,
    const unsigned short* __restrict__ kp,
    const unsigned short* __restrict__ vpt,
    unsigned short* __restrict__ attnb) {
  __shared__ __align__(16) unsigned short K_lds[32][32][16];  // [kr][key][ch]
  const int bid = blockIdx.x;
  const int win = bid & 63;
  const int sub = bid >> 6;
  const int qh = sub & 1, head = sub >> 1;
  const int wy = win >> 3, wx = win & 7;
  const int tid = threadIdx.x;
  const int wv = tid >> 6, l = tid & 63;
  const int lr = l & 15, lg = l >> 4;

  // ---- stage K: 1024 halo tokens x 16 ch (32B each), coalesced ----
#pragma unroll
  for (int it = 0; it < 4; it++) {
    const int idx = it * 256 + tid;
    const int krr = idx >> 5, key = idx & 31;
    const unsigned short* src =
        kp + ((size_t)(wy * 16 + krr) * 144 + wx * 16 + key) * 128 + head * 16;
    *(u32x4*)&K_lds[krr][key][0] = *(const u32x4*)src;
    *(u32x4*)&K_lds[krr][key][8] = *(const u32x4*)(src + 8);
  }

  // Q^T B-frags: col q = lr, k = hd = lg*8+e (real only k<16)
  bf16x8 qf[2];
#pragma unroll
  for (int qt = 0; qt < 2; qt++) {
    bf16x8 t = {};
    if (lg < 2) {
      const int qi = qh * 128 + wv * 32 + qt * 16 + lr;
      const int gh = wy * 16 + (qi >> 4), gw = wx * 16 + (qi & 15);
      t = *(const bf16x8*)(qb + ((size_t)(gh * 128 + gw)) * 128 + head * 16 + lg * 8);
    }
    qf[qt] = t;
  }

  bf16x8 ones;
#pragma unroll
  for (int e = 0; e < 8; e++) ones[e] = (short)0x3F80;   // bf16 1.0

  f32x4 acc[2] = {}, den[2] = {};

  const unsigned short* vrow =
      vpt + (size_t)(head * 16 + lr) * PADT + (size_t)(wy * 16) * 144 + wx * 16;

  __syncthreads();

  for (int kr = 0; kr < 32; kr++) {
    bf16x8 kf0 = {}, kf1 = {};
    if (lg < 2) {
      kf0 = *(const bf16x8*)&K_lds[kr][lr][lg * 8];
      kf1 = *(const bf16x8*)&K_lds[kr][16 + lr][lg * 8];
    }
    // V^T A-frag under sigma: word r = (V[lg*4+r][lr], V[16+lg*4+r][lr])
    const unsigned short* vr = vrow + kr * 144;
    const uint2 ua = *(const uint2*)(vr + lg * 4);        // tokens lg*4..+3
    const uint2 ub = *(const uint2*)(vr + 16 + lg * 4);   // tokens 16+lg*4..+3
    u32x4 vfw;
    vfw[0] = __builtin_amdgcn_perm(ub.x, ua.x, 0x05040100u);
    vfw[1] = __builtin_amdgcn_perm(ub.x, ua.x, 0x07060302u);
    vfw[2] = __builtin_amdgcn_perm(ub.y, ua.y, 0x05040100u);
    vfw[3] = __builtin_amdgcn_perm(ub.y, ua.y, 0x07060302u);
    const bf16x8 vfrag = __builtin_bit_cast(bf16x8, vfw);
#pragma unroll
    for (int qt = 0; qt < 2; qt++) {
      f32x4 s0 = {}, s1 = {};
      s0 = MFMA16(kf0, qf[qt], s0);   // P[key=lg*4+r][q=lr]
      s1 = MFMA16(kf1, qf[qt], s1);   // P[key=16+lg*4+r][q=lr]
      u32x4 pw;
#pragma unroll
      for (int r = 0; r < 4; r++)
        pw[r] = cvt_pk_bf16(__builtin_amdgcn_exp2f(s0[r]),
                            __builtin_amdgcn_exp2f(s1[r]));
      const bf16x8 pfrag = __builtin_bit_cast(bf16x8, pw);
      acc[qt] = MFMA16(vfrag, pfrag, acc[qt]);   // OUT^T[d][q]
      den[qt] = MFMA16(ones,  pfrag, den[qt]);   // every row = sum_key P
    }
  }

#pragma unroll
  for (int qt = 0; qt < 2; qt++) {
    const float inv = __builtin_amdgcn_rcpf(den[qt][0]);
    const int qi2 = qh * 128 + wv * 32 + qt * 16 + lr;
    const int gh2 = wy * 16 + (qi2 >> 4), gw2 = wx * 16 + (qi2 & 15);
    uint2 o;
    o.x = cvt_pk_bf16(acc[qt][0] * inv, acc[qt][1] * inv);
    o.y = cvt_pk_bf16(acc[qt][2] * inv, acc[qt][3] * inv);
    *(uint2*)(attnb + ((size_t)(gh2 * 128 + gw2)) * 128 + head * 16 + lg * 4) = o;
  }
}

// ------------------------------- launcher ----------------------------------
extern "C" void kernel_launch(void* const* d_in, const int* in_sizes, int n_in,
                              void* d_out, int out_size, void* d_ws, size_t ws_size,
                              hipStream_t stream) {
  const float* x      = (const float*)d_in[0];
  const float* ln1w   = (const float*)d_in[1];
  const float* ln1b   = (const float*)d_in[2];
  const float* qkv_w  = (const float*)d_in[3];
  const float* qkv_b  = (const float*)d_in[4];
  const float* proj_w = (const float*)d_in[5];
  const float* proj_b = (const float*)d_in[6];
  const float* ln2w   = (const float*)d_in[7];
  const float* ln2b   = (const float*)d_in[8];
  const float* fc1_w  = (const float*)d_in[9];
  const float* fc1_b  = (const float*)d_in[10];
  const float* fc2_w  = (const float*)d_in[11];
  const float* fc2_b  = (const float*)d_in[12];

  char* ws = (char*)d_ws;
  float*          xh_t = (float*)(ws + O_XHT);
  unsigned short* h1   = (unsigned short*)(ws + O_H1);
  unsigned short* qb   = (unsigned short*)(ws + O_QB);
  float*          xh1  = (float*)(ws + O_XH1);
  unsigned short* kp   = (unsigned short*)(ws + O_KP);
  unsigned short* vpt  = (unsigned short*)(ws + O_VPT);
  unsigned short* wb   = (unsigned short*)(ws + O_WB);
  unsigned short* attnb = h1;   // h1 dead after QKV GEMM consumed it
  unsigned short* h2    = qb;   // qb dead after attention
  float* outp = (float*)d_out;

  unsigned short* qkv_wb  = wb;            // 49152
  unsigned short* proj_wb = wb + 49152;    // 16384
  unsigned short* fc1_wb  = wb + 65536;    // 65536
  unsigned short* fc2_wb  = wb + 131072;   // 65536

  setup_kernel<<<337, 256, 0, stream>>>(qkv_w, proj_w, fc1_w, fc2_w, wb, kp, vpt);
  ln1_kernel<<<512, 256, 0, stream>>>(x, ln1w, ln1b, xh_t, h1);
  qkv_kernel<<<dim3(256, 6), 64, 0, stream>>>(h1, qkv_wb, qkv_b, qb, kp, vpt);
  attn_kernel<<<1024, 256, 0, stream>>>(qb, kp, vpt, attnb);
  projln2_kernel<<<1024, 256, 0, stream>>>(
      attnb, proj_wb, proj_b, xh_t, ln2w, ln2b, xh1, h2);
  mlp_kernel<<<256, 256, 0, stream>>>(h2, fc1_wb, fc1_b, fc2_wb, fc2_b, xh1, outp);
}

// Round 16
// 94.167 us; speedup vs baseline: 1.0911x; 1.0911x over previous
//
#include <hip/hip_runtime.h>
#include <hip/hip_bf16.h>

// ---------------------------------------------------------------------------
// EnhancedUFormerBlock: [setup || LN1] -> QKV(+V^T fold) -> halo attention ->
//                       proj(+res)+LN2 -> fused MLP(GELU+fc2+res) -> NCHW.
// Harness I/O dtype: float32 (per reference). Internals: bf16 MFMA.
// Only 16x16x32 MFMA fragment layouts are used (HW-validated rounds 2-8).
// attn: FROZEN at r13 (4w x 32q, K staged in LDS, pl P-staging, 1024 blocks,
// ~35.6us). Attn ladder record: 16q=71.8us; 32q=40.7us; 32q+K-LDS=35.6us;
// 32q sigma-PV=41.7us (ILP loss); 64q INCORRECT in 3 independent forms
// (r9 shared-pl 0.51, r10 disjoint-pl 0.49, r15 sigma-PV/no-LDS 0.54) --
// failure tracks qt-unroll depth, not memory subsystem; permanently closed.
// GEMMs: 1-wave 64x64 tiles (r11). MLP: fc1+GELU+fc2 fused in LDS (r13).
// r16: setup+ln1 merged into one launch (data-independent, run concurrently).
// ---------------------------------------------------------------------------

typedef __attribute__((ext_vector_type(8))) short bf16x8;
typedef __attribute__((ext_vector_type(4))) float f32x4;
typedef __attribute__((ext_vector_type(4))) unsigned int u32x4;

#define MFMA16(a, b, c) __builtin_amdgcn_mfma_f32_16x16x32_bf16((a), (b), (c), 0, 0, 0)

__device__ __forceinline__ float u2f(unsigned short u) {
  unsigned int x = ((unsigned int)u) << 16;
  return __builtin_bit_cast(float, x);
}
__device__ __forceinline__ unsigned short f2u(float f) {
  unsigned int x = __builtin_bit_cast(unsigned int, f);
  x += 0x7FFFu + ((x >> 16) & 1u);   // RNE
  return (unsigned short)(x >> 16);
}
__device__ __forceinline__ unsigned int cvt_pk_bf16(float lo, float hi) {
  unsigned int r;
  asm("v_cvt_pk_bf16_f32 %0, %1, %2" : "=v"(r) : "v"(lo), "v"(hi));
  return r;
}
__device__ __forceinline__ float gelu_f(float v) {
  const float y = 0.7978845608f * (v + 0.044715f * v * v * v);
  const float E = __builtin_amdgcn_exp2f(y * 2.8853900818f);
  return v - v * __builtin_amdgcn_rcpf(E + 1.0f);
}

#define QSCALE 0.36067376022224085f   // 0.25 * log2(e)

// ws layout (bytes). Aliases safe per kernel ordering:
//   attnb <- h1 (dead after QKV), h2 <- qb (dead after attn).
#define O_XHT 0ull                      // f32 residual 1 [16384][128]  8MB
#define O_H1  (8ull << 20)              // bf16 LN1 out   [16384][128]  4MB
#define O_QB  (12ull << 20)             // bf16 Q (pre-scaled)          4MB
#define O_XH1 (16ull << 20)             // f32 residual 2 [16384][128]  8MB
#define O_KP  (24ull << 20)             // bf16 K padded  [144*144][128]
#define O_VPT (O_KP + 5308416ull)       // bf16 V^T       [128][144*144]
#define O_WB  (O_KP + (16ull << 20))    // bf16 weights   ~384KB
#define PADT  20736                     // 144*144 padded tokens

// ------- merged pre-pass: weight cvt + pad zero (bx<337) | LN1 (bx>=337) ---
// The two halves are data-independent; merging lets them run concurrently.
__global__ __launch_bounds__(256) void pre_kernel(
    const float* __restrict__ a, const float* __restrict__ b,
    const float* __restrict__ c, const float* __restrict__ d,
    unsigned short* __restrict__ wb,
    unsigned short* __restrict__ kp, unsigned short* __restrict__ vpt,
    const float* __restrict__ x,
    const float* __restrict__ lw, const float* __restrict__ lb,
    float* __restrict__ xh_t, unsigned short* __restrict__ h1) {
  __shared__ float ld[128][33];
  const int bx = blockIdx.x, tid = threadIdx.x;
  if (bx < 192) {
    const int i = (bx * 256 + tid) * 4;
    const float* s; int lo;
    if (i < 49152)       { s = a; lo = 0; }
    else if (i < 65536)  { s = b; lo = 49152; }
    else if (i < 131072) { s = c; lo = 65536; }
    else                 { s = d; lo = 131072; }
    const float4 v = *(const float4*)(s + (i - lo));
    ushort4 o;
    o.x = f2u(v.x); o.y = f2u(v.y); o.z = f2u(v.z); o.w = f2u(v.w);
    *(ushort4*)(wb + i) = o;
  } else if (bx < 209) {
    const int idx = (bx - 192) * 256 + tid;
    if (idx >= 4352) return;
    int r, cc;
    if (idx < 2304) {               // top 8 + bottom 8 full rows (16 x 144)
      const int rr = idx / 144;
      r = (rr < 8) ? rr : rr + 128;
      cc = idx - rr * 144;
    } else {                        // side cols of rows 8..135 (128 x 16)
      const int i2 = idx - 2304;
      r = 8 + (i2 >> 4);
      const int c2 = i2 & 15;
      cc = (c2 < 8) ? c2 : c2 + 128;
    }
    const size_t off = ((size_t)r * 144 + cc) * 128;
    const u32x4 z = {};
#pragma unroll
    for (int k = 0; k < 16; k++) *(u32x4*)(kp + off + k * 8) = z;
  } else if (bx < 337) {
    const int ch = bx - 209;
    unsigned short* base = vpt + (size_t)ch * PADT;
    const u32x4 z = {};
    if (tid < 144) {
      *(u32x4*)(base + tid * 8) = z;            // top rows, tok 0..1151
      *(u32x4*)(base + 19584 + tid * 8) = z;    // bottom rows
    }
    const int hr = tid >> 1, side = tid & 1;    // side runs, rows 8..135
    *(u32x4*)(base + (hr + 8) * 144 + side * 136) = z;
  } else {
    // ---------------- LN1 + NCHW->NHWC via LDS transpose tile --------------
    const int t0 = (bx - 337) * 32;
    {
      const int cch = tid >> 1, th = (tid & 1) * 16;
      const float* src = x + (size_t)cch * 16384 + t0 + th;
#pragma unroll
      for (int i = 0; i < 4; i++) {
        const float4 v = *(const float4*)(src + i * 4);
        ld[cch][th + i * 4]     = v.x;
        ld[cch][th + i * 4 + 1] = v.y;
        ld[cch][th + i * 4 + 2] = v.z;
        ld[cch][th + i * 4 + 3] = v.w;
      }
    }
    __syncthreads();
    const int t = tid >> 3, cp = (tid & 7) * 16;
    float vals[16];
    float s = 0.f, q = 0.f;
#pragma unroll
    for (int i = 0; i < 16; i++) {
      const float v = ld[cp + i][t];
      vals[i] = v;
      s += v; q += v * v;
    }
    s += __shfl_xor(s, 1); q += __shfl_xor(q, 1);
    s += __shfl_xor(s, 2); q += __shfl_xor(q, 2);
    s += __shfl_xor(s, 4); q += __shfl_xor(q, 4);
    const float mu = s * 0.0078125f;
    const float rs = rsqrtf(q * 0.0078125f - mu * mu + 1e-5f);
    float* xrow = xh_t + (size_t)(t0 + t) * 128 + cp;
#pragma unroll
    for (int i = 0; i < 4; i++)
      *(float4*)(xrow + i * 4) =
          float4{vals[4*i], vals[4*i+1], vals[4*i+2], vals[4*i+3]};
    unsigned int pk[8];
#pragma unroll
    for (int k = 0; k < 8; k++) {
      const float y0 = (vals[2*k]   - mu) * rs * lw[cp + 2*k]   + lb[cp + 2*k];
      const float y1 = (vals[2*k+1] - mu) * rs * lw[cp + 2*k+1] + lb[cp + 2*k+1];
      pk[k] = cvt_pk_bf16(y0, y1);
    }
    unsigned int* hrow = (unsigned int*)(h1 + (size_t)(t0 + t) * 128 + cp);
    *(u32x4*)(hrow)     = u32x4{pk[0], pk[1], pk[2], pk[3]};
    *(u32x4*)(hrow + 4) = u32x4{pk[4], pk[5], pk[6], pk[7]};
  }
}

// ------------------------- QKV GEMM (1-wave 64x64) -------------------------
__global__ __launch_bounds__(64) void qkv_kernel(
    const unsigned short* __restrict__ A,
    const unsigned short* __restrict__ B,
    const float* __restrict__ bias,
    unsigned short* __restrict__ qb,
    unsigned short* __restrict__ kp,
    unsigned short* __restrict__ vpt) {
  const int tid = threadIdx.x;
  const int lr = tid & 15, lg = tid >> 4;
  const int mB = blockIdx.x * 64, nB = blockIdx.y * 64;
  f32x4 acc[4][4] = {};
  const unsigned short* Ab = A + (size_t)(mB + lr) * 128 + lg * 8;
  const unsigned short* Bb = B + (size_t)(nB + lr) * 128 + lg * 8;
  for (int k = 0; k < 128; k += 32) {
    bf16x8 a[4], b[4];
#pragma unroll
    for (int i = 0; i < 4; i++) {
      a[i] = *(const bf16x8*)(Ab + (size_t)i * 16 * 128 + k);
      b[i] = *(const bf16x8*)(Bb + (size_t)i * 16 * 128 + k);
    }
#pragma unroll
    for (int i = 0; i < 4; i++)
#pragma unroll
      for (int j = 0; j < 4; j++)
        acc[i][j] = MFMA16(a[i], b[j], acc[i][j]);
  }

  if (nB < 256) {   // Q (nB<128) or K (128<=nB<256): per-element stores
#pragma unroll
    for (int j = 0; j < 4; j++) {
      const int jj = nB + j * 16 + lr;
      const float bv = bias[jj];
#pragma unroll
      for (int i = 0; i < 4; i++)
#pragma unroll
        for (int r = 0; r < 4; r++) {
          const int ii = mB + i * 16 + lg * 4 + r;
          const float v = acc[i][j][r] + bv;
          if (jj < 128) {
            qb[(size_t)ii * 128 + jj] = f2u(v * QSCALE);
          } else {
            const int gh = ii >> 7, gw = ii & 127;
            const size_t prow = (size_t)(gh + 8) * 144 + (gw + 8);
            kp[prow * 128 + (jj - 128)] = f2u(v);
          }
        }
    }
  } else {          // V: LDS transpose -> coalesced V^T row stores
    __shared__ __align__(16) unsigned short tbv[64][72];
#pragma unroll
    for (int j = 0; j < 4; j++) {
      const int jl = j * 16 + lr;
      const float bv = bias[nB + jl];
#pragma unroll
      for (int i = 0; i < 4; i++)
#pragma unroll
        for (int r = 0; r < 4; r++) {
          const int il = i * 16 + lg * 4 + r;
          tbv[jl][il] = f2u(acc[i][j][r] + bv);
        }
    }
    __syncthreads();
    const int gh = mB >> 7, gw0 = mB & 127;     // 64|mB, no row wrap
    const size_t prow0 = (size_t)(gh + 8) * 144 + gw0 + 8;
    unsigned short* dst = vpt + (size_t)(nB - 256 + tid) * PADT + prow0;
#pragma unroll
    for (int t8 = 0; t8 < 8; t8++)
      *(u32x4*)(dst + t8 * 8) = *(const u32x4*)&tbv[tid][t8 * 8];
  }
}

// ---------------- proj GEMM + residual + LN2 (fused) -----------------------
__global__ __launch_bounds__(256) void projln2_kernel(
    const unsigned short* __restrict__ A,    // attnb
    const unsigned short* __restrict__ B,    // proj_wb
    const float* __restrict__ bias,
    const float* __restrict__ xh_t,
    const float* __restrict__ lw, const float* __restrict__ lb,
    float* __restrict__ xh1, unsigned short* __restrict__ h2) {
  __shared__ float sred[4][16][2];
  const int tid = threadIdx.x;
  const int w = tid >> 6, l = tid & 63;
  const int lr = l & 15, lg = l >> 4;
  const int mB = blockIdx.x * 16;
  const int n0 = w * 32;
  f32x4 acc[2] = {};
  const unsigned short* Ar = A + (size_t)(mB + lr) * 128 + lg * 8;
  const unsigned short* Br0 = B + (size_t)(n0 + lr) * 128 + lg * 8;
  const unsigned short* Br1 = Br0 + 16 * 128;
  for (int k = 0; k < 128; k += 32) {
    const bf16x8 a  = *(const bf16x8*)(Ar + k);
    const bf16x8 b0 = *(const bf16x8*)(Br0 + k);
    const bf16x8 b1 = *(const bf16x8*)(Br1 + k);
    acc[0] = MFMA16(a, b0, acc[0]);
    acc[1] = MFMA16(a, b1, acc[1]);
  }
  float vv[2][4];   // [j][r]
#pragma unroll
  for (int j = 0; j < 2; j++) {
    const int jj = n0 + j * 16 + lr;
    const float bv = bias[jj];
#pragma unroll
    for (int r = 0; r < 4; r++) {
      const int ii = mB + lg * 4 + r;
      const float v = acc[j][r] + bv + xh_t[(size_t)ii * 128 + jj];
      xh1[(size_t)ii * 128 + jj] = v;
      vv[j][r] = v;
    }
  }
#pragma unroll
  for (int r = 0; r < 4; r++) {
    float s = vv[0][r] + vv[1][r];
    float q = vv[0][r] * vv[0][r] + vv[1][r] * vv[1][r];
    s += __shfl_xor(s, 1); q += __shfl_xor(q, 1);
    s += __shfl_xor(s, 2); q += __shfl_xor(q, 2);
    s += __shfl_xor(s, 4); q += __shfl_xor(q, 4);
    s += __shfl_xor(s, 8); q += __shfl_xor(q, 8);
    if (lr == 0) {
      sred[w][lg * 4 + r][0] = s;
      sred[w][lg * 4 + r][1] = q;
    }
  }
  __syncthreads();
#pragma unroll
  for (int r = 0; r < 4; r++) {
    const int tok = lg * 4 + r;
    const float s = sred[0][tok][0] + sred[1][tok][0] +
                    sred[2][tok][0] + sred[3][tok][0];
    const float q = sred[0][tok][1] + sred[1][tok][1] +
                    sred[2][tok][1] + sred[3][tok][1];
    const float mu = s * 0.0078125f;
    const float rs = rsqrtf(q * 0.0078125f - mu * mu + 1e-5f);
#pragma unroll
    for (int j = 0; j < 2; j++) {
      const int jj = n0 + j * 16 + lr;
      const float y = (vv[j][r] - mu) * rs * lw[jj] + lb[jj];
      h2[(size_t)(mB + tok) * 128 + jj] = f2u(y);
    }
  }
}

// ------------------- fused MLP: fc1 + GELU + fc2 + residual ----------------
__global__ __launch_bounds__(256) void mlp_kernel(
    const unsigned short* __restrict__ h2,
    const unsigned short* __restrict__ fc1_wb,
    const float* __restrict__ fc1_b,
    const unsigned short* __restrict__ fc2_wb,
    const float* __restrict__ fc2_b,
    const float* __restrict__ xh1,
    float* __restrict__ outp) {
  __shared__ __align__(16) char smem[66560];
  unsigned short (*m_lds)[520] = (unsigned short(*)[520])smem;
  float (*tb)[68] = (float(*)[68])smem;

  const int tid = threadIdx.x;
  const int w = tid >> 6, l = tid & 63;
  const int lr = l & 15, lg = l >> 4;
  const int mB = blockIdx.x * 64;

  // ---- phase 1: m[t][n] = GELU(h2 @ fc1^T + b), wave w: n in [w*128, ...)
  {
    f32x4 acc[8][4] = {};
    const unsigned short* Ab = fc1_wb + (size_t)(w * 128 + lr) * 128 + lg * 8;
    const unsigned short* Bb = h2 + (size_t)(mB + lr) * 128 + lg * 8;
    for (int k = 0; k < 128; k += 32) {
      bf16x8 a[8], b[4];
#pragma unroll
      for (int i = 0; i < 8; i++)
        a[i] = *(const bf16x8*)(Ab + (size_t)i * 16 * 128 + k);
#pragma unroll
      for (int j = 0; j < 4; j++)
        b[j] = *(const bf16x8*)(Bb + (size_t)j * 16 * 128 + k);
#pragma unroll
      for (int i = 0; i < 8; i++)
#pragma unroll
        for (int j = 0; j < 4; j++)
          acc[i][j] = MFMA16(a[i], b[j], acc[i][j]);
    }
    // D[n][t]: n = w*128 + i*16 + lg*4 + r, t = j*16 + lr
#pragma unroll
    for (int i = 0; i < 8; i++) {
      const int n0 = w * 128 + i * 16 + lg * 4;
      const float4 b4 = *(const float4*)(fc1_b + n0);
#pragma unroll
      for (int j = 0; j < 4; j++) {
        const int t = j * 16 + lr;
        const float g0 = gelu_f(acc[i][j][0] + b4.x);
        const float g1 = gelu_f(acc[i][j][1] + b4.y);
        const float g2 = gelu_f(acc[i][j][2] + b4.z);
        const float g3 = gelu_f(acc[i][j][3] + b4.w);
        uint2 pk;
        pk.x = cvt_pk_bf16(g0, g1);
        pk.y = cvt_pk_bf16(g2, g3);
        *(uint2*)&m_lds[t][n0] = pk;
      }
    }
  }
  __syncthreads();

  // ---- phase 2: out[t][c] = m @ fc2^T + bias + xh1; wave w: c in [w*32,...)
  f32x4 acc2[4][2] = {};
  {
    const unsigned short* Bb = fc2_wb + (size_t)(w * 32 + lr) * 512 + lg * 8;
    for (int k = 0; k < 512; k += 32) {
      bf16x8 a[4], b[2];
#pragma unroll
      for (int i = 0; i < 4; i++)
        a[i] = *(const bf16x8*)&m_lds[i * 16 + lr][k + lg * 8];
#pragma unroll
      for (int j = 0; j < 2; j++)
        b[j] = *(const bf16x8*)(Bb + (size_t)j * 16 * 512 + k);
#pragma unroll
      for (int i = 0; i < 4; i++)
#pragma unroll
        for (int j = 0; j < 2; j++)
          acc2[i][j] = MFMA16(a[i], b[j], acc2[i][j]);
    }
  }
  __syncthreads();   // all waves done reading m before tb overwrites it

#pragma unroll
  for (int j = 0; j < 2; j++) {
    const int jj = w * 32 + j * 16 + lr;       // channel
    const float bv = fc2_b[jj];
#pragma unroll
    for (int i = 0; i < 4; i++)
#pragma unroll
      for (int r = 0; r < 4; r++) {
        const int il = i * 16 + lg * 4 + r;    // token within block
        tb[jj][il] = acc2[i][j][r] + bv +
                     xh1[(size_t)(mB + il) * 128 + jj];
      }
  }
  __syncthreads();
  {
    const int c = tid >> 1, seg = (tid & 1) * 32;
    float* op = outp + (size_t)c * 16384 + mB + seg;
#pragma unroll
    for (int q = 0; q < 8; q++)
      *(float4*)(op + q * 4) = *(const float4*)&tb[c][seg + q * 4];
  }
}

// ------------------------------ halo attention -----------------------------
// FROZEN r13 kernel: r8 structure + LDS-staged K. block = (win, head, qhalf),
// win=bid&63, 4 waves x 32 queries. K slice (32KB) staged cooperatively
// once; kf0/kf1 are ds_read_b128. V reads stay global (coalesced). P staged
// as packed (key s, key s+16) u32 via ONE ds_write_b128; PV A-frag = 2x
// ds_read_b128 + 4x v_perm. Denominator: den = mfma(pa, ones). Q pre-scaled
// by 0.25*log2(e): p = exp2(s) = exp(qk/4); zero-padded OOB keys give
// exp2(0)=1 terms, matching reference softmax exactly.
__global__ __launch_bounds__(256) void attn_kernel(
    const unsigned short* __restrict__ qb,
    const unsigned short* __restrict__ kp,
    const unsigned short* __restrict__ vpt,
    unsigned short* __restrict__ attnb) {
  __shared__ __align__(16) unsigned int pl[4][16][20];        // per-wave [q][slot]
  __shared__ __align__(16) unsigned short K_lds[32][32][16];  // [kr][key][ch]
  const int bid = blockIdx.x;
  const int win = bid & 63;
  const int sub = bid >> 6;
  const int qh = sub & 1, head = sub >> 1;
  const int wy = win >> 3, wx = win & 7;
  const int tid = threadIdx.x;
  const int wv = tid >> 6, l = tid & 63;
  const int lr = l & 15, lg = l >> 4;

  // ---- stage K: 1024 halo tokens x 16 ch (32B each), coalesced ----
#pragma unroll
  for (int it = 0; it < 4; it++) {
    const int idx = it * 256 + tid;
    const int krr = idx >> 5, key = idx & 31;
    const unsigned short* src =
        kp + ((size_t)(wy * 16 + krr) * 144 + wx * 16 + key) * 128 + head * 16;
    *(u32x4*)&K_lds[krr][key][0] = *(const u32x4*)src;
    *(u32x4*)&K_lds[krr][key][8] = *(const u32x4*)(src + 8);
  }

  // Q^T B-frags: col q = lr, k = hd = lg*8+e (real only k<16)
  bf16x8 qf[2];
#pragma unroll
  for (int qt = 0; qt < 2; qt++) {
    bf16x8 t = {};
    if (lg < 2) {
      const int qi = qh * 128 + wv * 32 + qt * 16 + lr;
      const int gh = wy * 16 + (qi >> 4), gw = wx * 16 + (qi & 15);
      t = *(const bf16x8*)(qb + ((size_t)(gh * 128 + gw)) * 128 + head * 16 + lg * 8);
    }
    qf[qt] = t;
  }

  bf16x8 ones;
#pragma unroll
  for (int e = 0; e < 8; e++) ones[e] = (short)0x3F80;   // bf16 1.0

  f32x4 acc[2] = {}, den[2] = {};
  unsigned int* wp = &pl[wv][lr][lg * 4];
  const unsigned int* rp = &pl[wv][lr][(lg & 1) * 8];
  const unsigned int psel = (lg >= 2) ? 0x07060302u : 0x05040100u;

  const unsigned short* vbase =
      vpt + (size_t)(head * 16 + lr) * PADT + (size_t)(wy * 16) * 144 + wx * 16 + lg * 8;

  __syncthreads();

  for (int kr = 0; kr < 32; kr++) {
    bf16x8 kf0 = {}, kf1 = {};
    if (lg < 2) {
      kf0 = *(const bf16x8*)&K_lds[kr][lr][lg * 8];
      kf1 = *(const bf16x8*)&K_lds[kr][16 + lr][lg * 8];
    }
    const bf16x8 vf = *(const bf16x8*)(vbase + kr * 144);
#pragma unroll
    for (int qt = 0; qt < 2; qt++) {
      f32x4 s0 = {}, s1 = {};
      s0 = MFMA16(kf0, qf[qt], s0);   // P[key=lg*4+r][q=lr]
      s1 = MFMA16(kf1, qf[qt], s1);   // P[key=16+lg*4+r][q=lr]
      unsigned int pk[4];
#pragma unroll
      for (int r = 0; r < 4; r++)
        pk[r] = cvt_pk_bf16(__builtin_amdgcn_exp2f(s0[r]),
                            __builtin_amdgcn_exp2f(s1[r]));
      *(u32x4*)wp = u32x4{pk[0], pk[1], pk[2], pk[3]};
      const u32x4 in0 = *(const u32x4*)(rp);
      const u32x4 in1 = *(const u32x4*)(rp + 4);
      u32x4 pa;
      pa[0] = __builtin_amdgcn_perm(in0[1], in0[0], psel);
      pa[1] = __builtin_amdgcn_perm(in0[3], in0[2], psel);
      pa[2] = __builtin_amdgcn_perm(in1[1], in1[0], psel);
      pa[3] = __builtin_amdgcn_perm(in1[3], in1[2], psel);
      const bf16x8 paf = __builtin_bit_cast(bf16x8, pa);
      acc[qt] = MFMA16(paf, vf, acc[qt]);
      den[qt] = MFMA16(paf, ones, den[qt]);
    }
  }

#pragma unroll
  for (int qt = 0; qt < 2; qt++)
#pragma unroll
    for (int r = 0; r < 4; r++) {
      const int q0 = qt * 16 + lg * 4 + r;
      const int qi2 = qh * 128 + wv * 32 + q0;
      const int gh2 = wy * 16 + (qi2 >> 4), gw2 = wx * 16 + (qi2 & 15);
      attnb[((size_t)(gh2 * 128 + gw2)) * 128 + head * 16 + lr] =
          f2u(acc[qt][r] * __builtin_amdgcn_rcpf(den[qt][r]));
    }
}

// ------------------------------- launcher ----------------------------------
extern "C" void kernel_launch(void* const* d_in, const int* in_sizes, int n_in,
                              void* d_out, int out_size, void* d_ws, size_t ws_size,
                              hipStream_t stream) {
  const float* x      = (const float*)d_in[0];
  const float* ln1w   = (const float*)d_in[1];
  const float* ln1b   = (const float*)d_in[2];
  const float* qkv_w  = (const float*)d_in[3];
  const float* qkv_b  = (const float*)d_in[4];
  const float* proj_w = (const float*)d_in[5];
  const float* proj_b = (const float*)d_in[6];
  const float* ln2w   = (const float*)d_in[7];
  const float* ln2b   = (const float*)d_in[8];
  const float* fc1_w  = (const float*)d_in[9];
  const float* fc1_b  = (const float*)d_in[10];
  const float* fc2_w  = (const float*)d_in[11];
  const float* fc2_b  = (const float*)d_in[12];

  char* ws = (char*)d_ws;
  float*          xh_t = (float*)(ws + O_XHT);
  unsigned short* h1   = (unsigned short*)(ws + O_H1);
  unsigned short* qb   = (unsigned short*)(ws + O_QB);
  float*          xh1  = (float*)(ws + O_XH1);
  unsigned short* kp   = (unsigned short*)(ws + O_KP);
  unsigned short* vpt  = (unsigned short*)(ws + O_VPT);
  unsigned short* wb   = (unsigned short*)(ws + O_WB);
  unsigned short* attnb = h1;   // h1 dead after QKV GEMM consumed it
  unsigned short* h2    = qb;   // qb dead after attention
  float* outp = (float*)d_out;

  unsigned short* qkv_wb  = wb;            // 49152
  unsigned short* proj_wb = wb + 49152;    // 16384
  unsigned short* fc1_wb  = wb + 65536;    // 65536
  unsigned short* fc2_wb  = wb + 131072;   // 65536

  pre_kernel<<<849, 256, 0, stream>>>(qkv_w, proj_w, fc1_w, fc2_w, wb, kp, vpt,
                                      x, ln1w, ln1b, xh_t, h1);
  qkv_kernel<<<dim3(256, 6), 64, 0, stream>>>(h1, qkv_wb, qkv_b, qb, kp, vpt);
  attn_kernel<<<1024, 256, 0, stream>>>(qb, kp, vpt, attnb);
  projln2_kernel<<<1024, 256, 0, stream>>>(
      attnb, proj_wb, proj_b, xh_t, ln2w, ln2b, xh1, h2);
  mlp_kernel<<<256, 256, 0, stream>>>(h2, fc1_wb, fc1_b, fc2_wb, fc2_b, xh1, outp);
}

// Round 17
// 88.467 us; speedup vs baseline: 1.1614x; 1.0644x over previous
//
#include <hip/hip_runtime.h>
#include <hip/hip_bf16.h>

// ---------------------------------------------------------------------------
// EnhancedUFormerBlock: [setup || LN1] -> QKV(+V^T fold) -> halo attention ->
//                       proj(+res)+LN2 -> fused MLP(GELU+fc2+res) -> NCHW.
// Harness I/O dtype: float32 (per reference). Internals: bf16 MFMA.
// Only 16x16x32 MFMA fragment layouts are used (HW-validated rounds 2-8).
// attn: r13 per-wave structure (4-deep... NO: qt=2 per wave, K-LDS, pl
// P-staging) at 8 waves/block (r17): both q-halves of a (win,head) share
// ONE K staging (was 2x), 512 blocks x 512 threads, 24 waves/CU.
// Per-wave code is byte-identical to the passing r13 kernel; only the
// wave->q mapping changed (qh = wv>>2). The qt-unroll axis stays at 2:
// 64q/wave INCORRECT in 3 independent forms (r9/r10/r15) -- closed.
// GEMMs: 1-wave 64x64 tiles (r11). MLP: fc1+GELU+fc2 fused in LDS (r13).
// ---------------------------------------------------------------------------

typedef __attribute__((ext_vector_type(8))) short bf16x8;
typedef __attribute__((ext_vector_type(4))) float f32x4;
typedef __attribute__((ext_vector_type(4))) unsigned int u32x4;

#define MFMA16(a, b, c) __builtin_amdgcn_mfma_f32_16x16x32_bf16((a), (b), (c), 0, 0, 0)

__device__ __forceinline__ float u2f(unsigned short u) {
  unsigned int x = ((unsigned int)u) << 16;
  return __builtin_bit_cast(float, x);
}
__device__ __forceinline__ unsigned short f2u(float f) {
  unsigned int x = __builtin_bit_cast(unsigned int, f);
  x += 0x7FFFu + ((x >> 16) & 1u);   // RNE
  return (unsigned short)(x >> 16);
}
__device__ __forceinline__ unsigned int cvt_pk_bf16(float lo, float hi) {
  unsigned int r;
  asm("v_cvt_pk_bf16_f32 %0, %1, %2" : "=v"(r) : "v"(lo), "v"(hi));
  return r;
}
__device__ __forceinline__ float gelu_f(float v) {
  const float y = 0.7978845608f * (v + 0.044715f * v * v * v);
  const float E = __builtin_amdgcn_exp2f(y * 2.8853900818f);
  return v - v * __builtin_amdgcn_rcpf(E + 1.0f);
}

#define QSCALE 0.36067376022224085f   // 0.25 * log2(e)

// ws layout (bytes). Aliases safe per kernel ordering:
//   attnb <- h1 (dead after QKV), h2 <- qb (dead after attn).
#define O_XHT 0ull                      // f32 residual 1 [16384][128]  8MB
#define O_H1  (8ull << 20)              // bf16 LN1 out   [16384][128]  4MB
#define O_QB  (12ull << 20)             // bf16 Q (pre-scaled)          4MB
#define O_XH1 (16ull << 20)             // f32 residual 2 [16384][128]  8MB
#define O_KP  (24ull << 20)             // bf16 K padded  [144*144][128]
#define O_VPT (O_KP + 5308416ull)       // bf16 V^T       [128][144*144]
#define O_WB  (O_KP + (16ull << 20))    // bf16 weights   ~384KB
#define PADT  20736                     // 144*144 padded tokens

// ------- merged pre-pass: weight cvt + pad zero (bx<337) | LN1 (bx>=337) ---
__global__ __launch_bounds__(256) void pre_kernel(
    const float* __restrict__ a, const float* __restrict__ b,
    const float* __restrict__ c, const float* __restrict__ d,
    unsigned short* __restrict__ wb,
    unsigned short* __restrict__ kp, unsigned short* __restrict__ vpt,
    const float* __restrict__ x,
    const float* __restrict__ lw, const float* __restrict__ lb,
    float* __restrict__ xh_t, unsigned short* __restrict__ h1) {
  __shared__ float ld[128][33];
  const int bx = blockIdx.x, tid = threadIdx.x;
  if (bx < 192) {
    const int i = (bx * 256 + tid) * 4;
    const float* s; int lo;
    if (i < 49152)       { s = a; lo = 0; }
    else if (i < 65536)  { s = b; lo = 49152; }
    else if (i < 131072) { s = c; lo = 65536; }
    else                 { s = d; lo = 131072; }
    const float4 v = *(const float4*)(s + (i - lo));
    ushort4 o;
    o.x = f2u(v.x); o.y = f2u(v.y); o.z = f2u(v.z); o.w = f2u(v.w);
    *(ushort4*)(wb + i) = o;
  } else if (bx < 209) {
    const int idx = (bx - 192) * 256 + tid;
    if (idx >= 4352) return;
    int r, cc;
    if (idx < 2304) {               // top 8 + bottom 8 full rows (16 x 144)
      const int rr = idx / 144;
      r = (rr < 8) ? rr : rr + 128;
      cc = idx - rr * 144;
    } else {                        // side cols of rows 8..135 (128 x 16)
      const int i2 = idx - 2304;
      r = 8 + (i2 >> 4);
      const int c2 = i2 & 15;
      cc = (c2 < 8) ? c2 : c2 + 128;
    }
    const size_t off = ((size_t)r * 144 + cc) * 128;
    const u32x4 z = {};
#pragma unroll
    for (int k = 0; k < 16; k++) *(u32x4*)(kp + off + k * 8) = z;
  } else if (bx < 337) {
    const int ch = bx - 209;
    unsigned short* base = vpt + (size_t)ch * PADT;
    const u32x4 z = {};
    if (tid < 144) {
      *(u32x4*)(base + tid * 8) = z;            // top rows, tok 0..1151
      *(u32x4*)(base + 19584 + tid * 8) = z;    // bottom rows
    }
    const int hr = tid >> 1, side = tid & 1;    // side runs, rows 8..135
    *(u32x4*)(base + (hr + 8) * 144 + side * 136) = z;
  } else {
    // ---------------- LN1 + NCHW->NHWC via LDS transpose tile --------------
    const int t0 = (bx - 337) * 32;
    {
      const int cch = tid >> 1, th = (tid & 1) * 16;
      const float* src = x + (size_t)cch * 16384 + t0 + th;
#pragma unroll
      for (int i = 0; i < 4; i++) {
        const float4 v = *(const float4*)(src + i * 4);
        ld[cch][th + i * 4]     = v.x;
        ld[cch][th + i * 4 + 1] = v.y;
        ld[cch][th + i * 4 + 2] = v.z;
        ld[cch][th + i * 4 + 3] = v.w;
      }
    }
    __syncthreads();
    const int t = tid >> 3, cp = (tid & 7) * 16;
    float vals[16];
    float s = 0.f, q = 0.f;
#pragma unroll
    for (int i = 0; i < 16; i++) {
      const float v = ld[cp + i][t];
      vals[i] = v;
      s += v; q += v * v;
    }
    s += __shfl_xor(s, 1); q += __shfl_xor(q, 1);
    s += __shfl_xor(s, 2); q += __shfl_xor(q, 2);
    s += __shfl_xor(s, 4); q += __shfl_xor(q, 4);
    const float mu = s * 0.0078125f;
    const float rs = rsqrtf(q * 0.0078125f - mu * mu + 1e-5f);
    float* xrow = xh_t + (size_t)(t0 + t) * 128 + cp;
#pragma unroll
    for (int i = 0; i < 4; i++)
      *(float4*)(xrow + i * 4) =
          float4{vals[4*i], vals[4*i+1], vals[4*i+2], vals[4*i+3]};
    unsigned int pk[8];
#pragma unroll
    for (int k = 0; k < 8; k++) {
      const float y0 = (vals[2*k]   - mu) * rs * lw[cp + 2*k]   + lb[cp + 2*k];
      const float y1 = (vals[2*k+1] - mu) * rs * lw[cp + 2*k+1] + lb[cp + 2*k+1];
      pk[k] = cvt_pk_bf16(y0, y1);
    }
    unsigned int* hrow = (unsigned int*)(h1 + (size_t)(t0 + t) * 128 + cp);
    *(u32x4*)(hrow)     = u32x4{pk[0], pk[1], pk[2], pk[3]};
    *(u32x4*)(hrow + 4) = u32x4{pk[4], pk[5], pk[6], pk[7]};
  }
}

// ------------------------- QKV GEMM (1-wave 64x64) -------------------------
__global__ __launch_bounds__(64) void qkv_kernel(
    const unsigned short* __restrict__ A,
    const unsigned short* __restrict__ B,
    const float* __restrict__ bias,
    unsigned short* __restrict__ qb,
    unsigned short* __restrict__ kp,
    unsigned short* __restrict__ vpt) {
  const int tid = threadIdx.x;
  const int lr = tid & 15, lg = tid >> 4;
  const int mB = blockIdx.x * 64, nB = blockIdx.y * 64;
  f32x4 acc[4][4] = {};
  const unsigned short* Ab = A + (size_t)(mB + lr) * 128 + lg * 8;
  const unsigned short* Bb = B + (size_t)(nB + lr) * 128 + lg * 8;
  for (int k = 0; k < 128; k += 32) {
    bf16x8 a[4], b[4];
#pragma unroll
    for (int i = 0; i < 4; i++) {
      a[i] = *(const bf16x8*)(Ab + (size_t)i * 16 * 128 + k);
      b[i] = *(const bf16x8*)(Bb + (size_t)i * 16 * 128 + k);
    }
#pragma unroll
    for (int i = 0; i < 4; i++)
#pragma unroll
      for (int j = 0; j < 4; j++)
        acc[i][j] = MFMA16(a[i], b[j], acc[i][j]);
  }

  if (nB < 256) {   // Q (nB<128) or K (128<=nB<256): per-element stores
#pragma unroll
    for (int j = 0; j < 4; j++) {
      const int jj = nB + j * 16 + lr;
      const float bv = bias[jj];
#pragma unroll
      for (int i = 0; i < 4; i++)
#pragma unroll
        for (int r = 0; r < 4; r++) {
          const int ii = mB + i * 16 + lg * 4 + r;
          const float v = acc[i][j][r] + bv;
          if (jj < 128) {
            qb[(size_t)ii * 128 + jj] = f2u(v * QSCALE);
          } else {
            const int gh = ii >> 7, gw = ii & 127;
            const size_t prow = (size_t)(gh + 8) * 144 + (gw + 8);
            kp[prow * 128 + (jj - 128)] = f2u(v);
          }
        }
    }
  } else {          // V: LDS transpose -> coalesced V^T row stores
    __shared__ __align__(16) unsigned short tbv[64][72];
#pragma unroll
    for (int j = 0; j < 4; j++) {
      const int jl = j * 16 + lr;
      const float bv = bias[nB + jl];
#pragma unroll
      for (int i = 0; i < 4; i++)
#pragma unroll
        for (int r = 0; r < 4; r++) {
          const int il = i * 16 + lg * 4 + r;
          tbv[jl][il] = f2u(acc[i][j][r] + bv);
        }
    }
    __syncthreads();
    const int gh = mB >> 7, gw0 = mB & 127;     // 64|mB, no row wrap
    const size_t prow0 = (size_t)(gh + 8) * 144 + gw0 + 8;
    unsigned short* dst = vpt + (size_t)(nB - 256 + tid) * PADT + prow0;
#pragma unroll
    for (int t8 = 0; t8 < 8; t8++)
      *(u32x4*)(dst + t8 * 8) = *(const u32x4*)&tbv[tid][t8 * 8];
  }
}

// ---------------- proj GEMM + residual + LN2 (fused) -----------------------
__global__ __launch_bounds__(256) void projln2_kernel(
    const unsigned short* __restrict__ A,    // attnb
    const unsigned short* __restrict__ B,    // proj_wb
    const float* __restrict__ bias,
    const float* __restrict__ xh_t,
    const float* __restrict__ lw, const float* __restrict__ lb,
    float* __restrict__ xh1, unsigned short* __restrict__ h2) {
  __shared__ float sred[4][16][2];
  const int tid = threadIdx.x;
  const int w = tid >> 6, l = tid & 63;
  const int lr = l & 15, lg = l >> 4;
  const int mB = blockIdx.x * 16;
  const int n0 = w * 32;
  f32x4 acc[2] = {};
  const unsigned short* Ar = A + (size_t)(mB + lr) * 128 + lg * 8;
  const unsigned short* Br0 = B + (size_t)(n0 + lr) * 128 + lg * 8;
  const unsigned short* Br1 = Br0 + 16 * 128;
  for (int k = 0; k < 128; k += 32) {
    const bf16x8 a  = *(const bf16x8*)(Ar + k);
    const bf16x8 b0 = *(const bf16x8*)(Br0 + k);
    const bf16x8 b1 = *(const bf16x8*)(Br1 + k);
    acc[0] = MFMA16(a, b0, acc[0]);
    acc[1] = MFMA16(a, b1, acc[1]);
  }
  float vv[2][4];   // [j][r]
#pragma unroll
  for (int j = 0; j < 2; j++) {
    const int jj = n0 + j * 16 + lr;
    const float bv = bias[jj];
#pragma unroll
    for (int r = 0; r < 4; r++) {
      const int ii = mB + lg * 4 + r;
      const float v = acc[j][r] + bv + xh_t[(size_t)ii * 128 + jj];
      xh1[(size_t)ii * 128 + jj] = v;
      vv[j][r] = v;
    }
  }
#pragma unroll
  for (int r = 0; r < 4; r++) {
    float s = vv[0][r] + vv[1][r];
    float q = vv[0][r] * vv[0][r] + vv[1][r] * vv[1][r];
    s += __shfl_xor(s, 1); q += __shfl_xor(q, 1);
    s += __shfl_xor(s, 2); q += __shfl_xor(q, 2);
    s += __shfl_xor(s, 4); q += __shfl_xor(q, 4);
    s += __shfl_xor(s, 8); q += __shfl_xor(q, 8);
    if (lr == 0) {
      sred[w][lg * 4 + r][0] = s;
      sred[w][lg * 4 + r][1] = q;
    }
  }
  __syncthreads();
#pragma unroll
  for (int r = 0; r < 4; r++) {
    const int tok = lg * 4 + r;
    const float s = sred[0][tok][0] + sred[1][tok][0] +
                    sred[2][tok][0] + sred[3][tok][0];
    const float q = sred[0][tok][1] + sred[1][tok][1] +
                    sred[2][tok][1] + sred[3][tok][1];
    const float mu = s * 0.0078125f;
    const float rs = rsqrtf(q * 0.0078125f - mu * mu + 1e-5f);
#pragma unroll
    for (int j = 0; j < 2; j++) {
      const int jj = n0 + j * 16 + lr;
      const float y = (vv[j][r] - mu) * rs * lw[jj] + lb[jj];
      h2[(size_t)(mB + tok) * 128 + jj] = f2u(y);
    }
  }
}

// ------------------- fused MLP: fc1 + GELU + fc2 + residual ----------------
__global__ __launch_bounds__(256) void mlp_kernel(
    const unsigned short* __restrict__ h2,
    const unsigned short* __restrict__ fc1_wb,
    const float* __restrict__ fc1_b,
    const unsigned short* __restrict__ fc2_wb,
    const float* __restrict__ fc2_b,
    const float* __restrict__ xh1,
    float* __restrict__ outp) {
  __shared__ __align__(16) char smem[66560];
  unsigned short (*m_lds)[520] = (unsigned short(*)[520])smem;
  float (*tb)[68] = (float(*)[68])smem;

  const int tid = threadIdx.x;
  const int w = tid >> 6, l = tid & 63;
  const int lr = l & 15, lg = l >> 4;
  const int mB = blockIdx.x * 64;

  // ---- phase 1: m[t][n] = GELU(h2 @ fc1^T + b), wave w: n in [w*128, ...)
  {
    f32x4 acc[8][4] = {};
    const unsigned short* Ab = fc1_wb + (size_t)(w * 128 + lr) * 128 + lg * 8;
    const unsigned short* Bb = h2 + (size_t)(mB + lr) * 128 + lg * 8;
    for (int k = 0; k < 128; k += 32) {
      bf16x8 a[8], b[4];
#pragma unroll
      for (int i = 0; i < 8; i++)
        a[i] = *(const bf16x8*)(Ab + (size_t)i * 16 * 128 + k);
#pragma unroll
      for (int j = 0; j < 4; j++)
        b[j] = *(const bf16x8*)(Bb + (size_t)j * 16 * 128 + k);
#pragma unroll
      for (int i = 0; i < 8; i++)
#pragma unroll
        for (int j = 0; j < 4; j++)
          acc[i][j] = MFMA16(a[i], b[j], acc[i][j]);
    }
    // D[n][t]: n = w*128 + i*16 + lg*4 + r, t = j*16 + lr
#pragma unroll
    for (int i = 0; i < 8; i++) {
      const int n0 = w * 128 + i * 16 + lg * 4;
      const float4 b4 = *(const float4*)(fc1_b + n0);
#pragma unroll
      for (int j = 0; j < 4; j++) {
        const int t = j * 16 + lr;
        const float g0 = gelu_f(acc[i][j][0] + b4.x);
        const float g1 = gelu_f(acc[i][j][1] + b4.y);
        const float g2 = gelu_f(acc[i][j][2] + b4.z);
        const float g3 = gelu_f(acc[i][j][3] + b4.w);
        uint2 pk;
        pk.x = cvt_pk_bf16(g0, g1);
        pk.y = cvt_pk_bf16(g2, g3);
        *(uint2*)&m_lds[t][n0] = pk;
      }
    }
  }
  __syncthreads();

  // ---- phase 2: out[t][c] = m @ fc2^T + bias + xh1; wave w: c in [w*32,...)
  f32x4 acc2[4][2] = {};
  {
    const unsigned short* Bb = fc2_wb + (size_t)(w * 32 + lr) * 512 + lg * 8;
    for (int k = 0; k < 512; k += 32) {
      bf16x8 a[4], b[2];
#pragma unroll
      for (int i = 0; i < 4; i++)
        a[i] = *(const bf16x8*)&m_lds[i * 16 + lr][k + lg * 8];
#pragma unroll
      for (int j = 0; j < 2; j++)
        b[j] = *(const bf16x8*)(Bb + (size_t)j * 16 * 512 + k);
#pragma unroll
      for (int i = 0; i < 4; i++)
#pragma unroll
        for (int j = 0; j < 2; j++)
          acc2[i][j] = MFMA16(a[i], b[j], acc2[i][j]);
    }
  }
  __syncthreads();   // all waves done reading m before tb overwrites it

#pragma unroll
  for (int j = 0; j < 2; j++) {
    const int jj = w * 32 + j * 16 + lr;       // channel
    const float bv = fc2_b[jj];
#pragma unroll
    for (int i = 0; i < 4; i++)
#pragma unroll
      for (int r = 0; r < 4; r++) {
        const int il = i * 16 + lg * 4 + r;    // token within block
        tb[jj][il] = acc2[i][j][r] + bv +
                     xh1[(size_t)(mB + il) * 128 + jj];
      }
  }
  __syncthreads();
  {
    const int c = tid >> 1, seg = (tid & 1) * 32;
    float* op = outp + (size_t)c * 16384 + mB + seg;
#pragma unroll
    for (int q = 0; q < 8; q++)
      *(float4*)(op + q * 4) = *(const float4*)&tb[c][seg + q * 4];
  }
}

// ------------------------------ halo attention -----------------------------
// r13 per-wave structure at 8 waves/block (r17): block = (win, head),
// win = bid&63, 512 blocks x 512 threads. Wave wv handles queries
// (wv>>2)*128 + (wv&3)*32 .. +32 (qt = 0..1, the validated unroll depth).
// The 32KB K slice is staged ONCE per (win, head) -- halves K staging
// traffic vs r13's two q-half blocks. kf0/kf1 via ds_read_b128; V reads
// global (coalesced). P staged as packed (key s, key s+16) u32 via ONE
// ds_write_b128 into the per-wave pl row; PV A-frag = 2x ds_read_b128 +
// 4x v_perm. Denominator: den = mfma(pa, ones). Q pre-scaled by
// 0.25*log2(e): p = exp2(s) = exp(qk/4); zero-padded OOB keys give
// exp2(0)=1 terms, matching reference softmax exactly.
__global__ __launch_bounds__(512) void attn_kernel(
    const unsigned short* __restrict__ qb,
    const unsigned short* __restrict__ kp,
    const unsigned short* __restrict__ vpt,
    unsigned short* __restrict__ attnb) {
  __shared__ __align__(16) unsigned int pl[8][16][20];        // per-wave [q][slot]
  __shared__ __align__(16) unsigned short K_lds[32][32][16];  // [kr][key][ch]
  const int bid = blockIdx.x;
  const int win = bid & 63;
  const int head = bid >> 6;
  const int wy = win >> 3, wx = win & 7;
  const int tid = threadIdx.x;
  const int wv = tid >> 6, l = tid & 63;
  const int qh = wv >> 2, ws2 = wv & 3;
  const int lr = l & 15, lg = l >> 4;

  // ---- stage K: 1024 halo tokens x 16 ch (32B each), coalesced ----
#pragma unroll
  for (int it = 0; it < 2; it++) {
    const int idx = it * 512 + tid;
    const int krr = idx >> 5, key = idx & 31;
    const unsigned short* src =
        kp + ((size_t)(wy * 16 + krr) * 144 + wx * 16 + key) * 128 + head * 16;
    *(u32x4*)&K_lds[krr][key][0] = *(const u32x4*)src;
    *(u32x4*)&K_lds[krr][key][8] = *(const u32x4*)(src + 8);
  }

  // Q^T B-frags: col q = lr, k = hd = lg*8+e (real only k<16)
  bf16x8 qf[2];
#pragma unroll
  for (int qt = 0; qt < 2; qt++) {
    bf16x8 t = {};
    if (lg < 2) {
      const int qi = qh * 128 + ws2 * 32 + qt * 16 + lr;
      const int gh = wy * 16 + (qi >> 4), gw = wx * 16 + (qi & 15);
      t = *(const bf16x8*)(qb + ((size_t)(gh * 128 + gw)) * 128 + head * 16 + lg * 8);
    }
    qf[qt] = t;
  }

  bf16x8 ones;
#pragma unroll
  for (int e = 0; e < 8; e++) ones[e] = (short)0x3F80;   // bf16 1.0

  f32x4 acc[2] = {}, den[2] = {};
  unsigned int* wp = &pl[wv][lr][lg * 4];
  const unsigned int* rp = &pl[wv][lr][(lg & 1) * 8];
  const unsigned int psel = (lg >= 2) ? 0x07060302u : 0x05040100u;

  const unsigned short* vbase =
      vpt + (size_t)(head * 16 + lr) * PADT + (size_t)(wy * 16) * 144 + wx * 16 + lg * 8;

  __syncthreads();

  for (int kr = 0; kr < 32; kr++) {
    bf16x8 kf0 = {}, kf1 = {};
    if (lg < 2) {
      kf0 = *(const bf16x8*)&K_lds[kr][lr][lg * 8];
      kf1 = *(const bf16x8*)&K_lds[kr][16 + lr][lg * 8];
    }
    const bf16x8 vf = *(const bf16x8*)(vbase + kr * 144);
#pragma unroll
    for (int qt = 0; qt < 2; qt++) {
      f32x4 s0 = {}, s1 = {};
      s0 = MFMA16(kf0, qf[qt], s0);   // P[key=lg*4+r][q=lr]
      s1 = MFMA16(kf1, qf[qt], s1);   // P[key=16+lg*4+r][q=lr]
      unsigned int pk[4];
#pragma unroll
      for (int r = 0; r < 4; r++)
        pk[r] = cvt_pk_bf16(__builtin_amdgcn_exp2f(s0[r]),
                            __builtin_amdgcn_exp2f(s1[r]));
      *(u32x4*)wp = u32x4{pk[0], pk[1], pk[2], pk[3]};
      const u32x4 in0 = *(const u32x4*)(rp);
      const u32x4 in1 = *(const u32x4*)(rp + 4);
      u32x4 pa;
      pa[0] = __builtin_amdgcn_perm(in0[1], in0[0], psel);
      pa[1] = __builtin_amdgcn_perm(in0[3], in0[2], psel);
      pa[2] = __builtin_amdgcn_perm(in1[1], in1[0], psel);
      pa[3] = __builtin_amdgcn_perm(in1[3], in1[2], psel);
      const bf16x8 paf = __builtin_bit_cast(bf16x8, pa);
      acc[qt] = MFMA16(paf, vf, acc[qt]);
      den[qt] = MFMA16(paf, ones, den[qt]);
    }
  }

#pragma unroll
  for (int qt = 0; qt < 2; qt++)
#pragma unroll
    for (int r = 0; r < 4; r++) {
      const int q0 = qt * 16 + lg * 4 + r;
      const int qi2 = qh * 128 + ws2 * 32 + q0;
      const int gh2 = wy * 16 + (qi2 >> 4), gw2 = wx * 16 + (qi2 & 15);
      attnb[((size_t)(gh2 * 128 + gw2)) * 128 + head * 16 + lr] =
          f2u(acc[qt][r] * __builtin_amdgcn_rcpf(den[qt][r]));
    }
}

// ------------------------------- launcher ----------------------------------
extern "C" void kernel_launch(void* const* d_in, const int* in_sizes, int n_in,
                              void* d_out, int out_size, void* d_ws, size_t ws_size,
                              hipStream_t stream) {
  const float* x      = (const float*)d_in[0];
  const float* ln1w   = (const float*)d_in[1];
  const float* ln1b   = (const float*)d_in[2];
  const float* qkv_w  = (const float*)d_in[3];
  const float* qkv_b  = (const float*)d_in[4];
  const float* proj_w = (const float*)d_in[5];
  const float* proj_b = (const float*)d_in[6];
  const float* ln2w   = (const float*)d_in[7];
  const float* ln2b   = (const float*)d_in[8];
  const float* fc1_w  = (const float*)d_in[9];
  const float* fc1_b  = (const float*)d_in[10];
  const float* fc2_w  = (const float*)d_in[11];
  const float* fc2_b  = (const float*)d_in[12];

  char* ws = (char*)d_ws;
  float*          xh_t = (float*)(ws + O_XHT);
  unsigned short* h1   = (unsigned short*)(ws + O_H1);
  unsigned short* qb   = (unsigned short*)(ws + O_QB);
  float*          xh1  = (float*)(ws + O_XH1);
  unsigned short* kp   = (unsigned short*)(ws + O_KP);
  unsigned short* vpt  = (unsigned short*)(ws + O_VPT);
  unsigned short* wb   = (unsigned short*)(ws + O_WB);
  unsigned short* attnb = h1;   // h1 dead after QKV GEMM consumed it
  unsigned short* h2    = qb;   // qb dead after attention
  float* outp = (float*)d_out;

  unsigned short* qkv_wb  = wb;            // 49152
  unsigned short* proj_wb = wb + 49152;    // 16384
  unsigned short* fc1_wb  = wb + 65536;    // 65536
  unsigned short* fc2_wb  = wb + 131072;   // 65536

  pre_kernel<<<849, 256, 0, stream>>>(qkv_w, proj_w, fc1_w, fc2_w, wb, kp, vpt,
                                      x, ln1w, ln1b, xh_t, h1);
  qkv_kernel<<<dim3(256, 6), 64, 0, stream>>>(h1, qkv_wb, qkv_b, qb, kp, vpt);
  attn_kernel<<<512, 512, 0, stream>>>(qb, kp, vpt, attnb);
  projln2_kernel<<<1024, 256, 0, stream>>>(
      attnb, proj_wb, proj_b, xh_t, ln2w, ln2b, xh1, h2);
  mlp_kernel<<<256, 256, 0, stream>>>(h2, fc1_wb, fc1_b, fc2_wb, fc2_b, xh1, outp);
}